// Round 2
// baseline (682.178 us; speedup 1.0000x reference)
//
#include <hip/hip_runtime.h>
#include <stdint.h>

typedef __attribute__((ext_vector_type(8))) short short8;
typedef __attribute__((ext_vector_type(4))) float f32x4;

#define T_   16
#define N_   2048
#define E_   16384
#define NT   32768      // T*N
#define EALL 262144     // T*E
#define EL_  8192

static __device__ __forceinline__ short f2bf(float f){
  union { float f; uint32_t u; } v; v.f = f;
  uint32_t r = (v.u + 0x7FFFu + ((v.u >> 16) & 1u)) >> 16;
  return (short)r;
}
static __device__ __forceinline__ float lrelu(float x){ return x > 0.f ? x : 0.2f*x; }

// ---------------- init: zero cnt + fcsum (independent work, fused) ----------------------
__global__ void k_init(const float* __restrict__ fcw, short* __restrict__ wbf,
                       int* __restrict__ cnt){
  int b = blockIdx.x;
  if(b < 128){
    cnt[b*256 + threadIdx.x] = 0;
  } else {
    int id = (b-128)*256 + threadIdx.x;      // < N_*128 = 262144? (1024 blocks)
    int j = id >> 7, k = id & 127;
    wbf[id] = f2bf(fcw[j*256 + k] + fcw[j*256 + 128 + k]);
  }
}

// ---------------- CSR build: key = t*2048 + dst; value packs (eid<<11)|src -------------
__global__ void k_cnt(const int* __restrict__ ei, int* __restrict__ cnt){
  int id = blockIdx.x*256 + threadIdx.x;
  if(id >= EALL) return;
  int t = id >> 14, e = id & (E_-1);
  int d = ei[t*2*E_ + E_ + e];
  atomicAdd(&cnt[t*N_ + d], 1);
}
__global__ __launch_bounds__(1024) void k_scan(const int* __restrict__ cnt,
                                               int* __restrict__ off, int* __restrict__ cur){
  __shared__ int part[1024];
  int tid = threadIdx.x;
  int base = tid*32;
  int loc[32]; int s = 0;
#pragma unroll
  for(int i=0;i<32;i++){ loc[i] = s; s += cnt[base+i]; }
  part[tid] = s; __syncthreads();
  for(int d=1; d<1024; d<<=1){
    int v = (tid>=d) ? part[tid-d] : 0;
    __syncthreads();
    part[tid] += v;
    __syncthreads();
  }
  int pre = (tid==0) ? 0 : part[tid-1];
#pragma unroll
  for(int i=0;i<32;i++){ int v = pre + loc[i]; off[base+i] = v; cur[base+i] = v; }
  if(tid == 1023) off[NT] = part[1023];
}
__global__ void k_fill(const int* __restrict__ ei, int* __restrict__ cur, int* __restrict__ csr){
  int id = blockIdx.x*256 + threadIdx.x;
  if(id >= EALL) return;
  int t = id >> 14, e = id & (E_-1);
  int s = ei[t*2*E_ + e];
  int d = ei[t*2*E_ + E_ + e];
  int pos = atomicAdd(&cur[t*N_ + d], 1);
  csr[pos] = (id << 11) | s;          // eid (18b) | src (11b)
}

// dinv[node] = 1/sqrt(1 + sum ew over incoming edges); csr-prefetch pipelined
__global__ void k_degg(const float* __restrict__ ew, const int* __restrict__ off,
                       const int* __restrict__ csr, float* __restrict__ dinv){
  int n = blockIdx.x*256 + threadIdx.x;
  if(n >= NT) return;
  int beg = off[n], end = off[n+1];
  float s = 1.0f;
  if(beg < end){
    int v = csr[beg];
    for(int k=beg; k<end; k++){
      int vn = (k+1<end) ? csr[k+1] : 0;
      s += ew[v >> 11];
      v = vn;
    }
  }
  dinv[n] = rsqrtf(s);
}

// per-edge GCN coefficient (shared by both GCN layers)
__global__ void k_coef(const int* __restrict__ ei, const float* __restrict__ ew,
                       const float* __restrict__ dinv, float* __restrict__ coef){
  int id = blockIdx.x*256 + threadIdx.x;
  if(id >= EALL) return;
  int t = id >> 14, e = id & (E_-1);
  int s = ei[t*2*E_ + e];
  int d = ei[t*2*E_ + E_ + e];
  coef[id] = dinv[t*N_ + s] * ew[id] * dinv[t*N_ + d];
}

// ---------------- MFMA GEMM: C[M,N] = act(A[M,K]) @ B[N,K]^T (+bias)(+relu) -------------
template<int TM,int TN,bool PREACT,bool EBIAS,bool ERELU,bool OBF16>
__global__ __launch_bounds__(256) void gemm_bt(
    const float* __restrict__ A, const float* __restrict__ ab,
    const float* __restrict__ B, const float* __restrict__ bias,
    float* __restrict__ Cf, short* __restrict__ Cb, int K, int N)
{
  const int lane = threadIdx.x & 63;
  const int wv   = threadIdx.x >> 6;
  const int wi = wv >> 1, wj = wv & 1;
  const int q = lane >> 4, r = lane & 15;
  const int m0 = blockIdx.y * (2*TM*16) + wi * (TM*16);
  const int n0 = blockIdx.x * (2*TN*16) + wj * (TN*16);

  f32x4 acc[TM][TN];
#pragma unroll
  for(int i=0;i<TM;i++)
#pragma unroll
    for(int j=0;j<TN;j++) acc[i][j] = (f32x4){0.f,0.f,0.f,0.f};

  for(int k0=0;k0<K;k0+=32){
    const int ka = k0 + q*8;
    short8 af[TM], bfr[TN];
#pragma unroll
    for(int i=0;i<TM;i++){
      const float* p = A + (size_t)(m0 + i*16 + r)*K + ka;
      float4 u0 = *(const float4*)p;
      float4 u1 = *(const float4*)(p+4);
      float vv[8] = {u0.x,u0.y,u0.z,u0.w,u1.x,u1.y,u1.z,u1.w};
      if (PREACT){
        const float* bb = ab + ka;
        float4 b0 = *(const float4*)bb;
        float4 b1 = *(const float4*)(bb+4);
        float bv[8] = {b0.x,b0.y,b0.z,b0.w,b1.x,b1.y,b1.z,b1.w};
#pragma unroll
        for(int u=0;u<8;u++) vv[u] = fmaxf(vv[u]+bv[u], 0.f);
      }
      short8 s;
#pragma unroll
      for(int u=0;u<8;u++) s[u] = f2bf(vv[u]);
      af[i] = s;
    }
#pragma unroll
    for(int j=0;j<TN;j++){
      const float* p = B + (size_t)(n0 + j*16 + r)*K + ka;
      float4 u0 = *(const float4*)p;
      float4 u1 = *(const float4*)(p+4);
      float vv[8] = {u0.x,u0.y,u0.z,u0.w,u1.x,u1.y,u1.z,u1.w};
      short8 s;
#pragma unroll
      for(int u=0;u<8;u++) s[u] = f2bf(vv[u]);
      bfr[j] = s;
    }
#pragma unroll
    for(int i=0;i<TM;i++)
#pragma unroll
      for(int j=0;j<TN;j++)
        acc[i][j] = __builtin_amdgcn_mfma_f32_16x16x32_bf16(af[i], bfr[j], acc[i][j], 0,0,0);
  }

#pragma unroll
  for(int i=0;i<TM;i++){
#pragma unroll
    for(int j=0;j<TN;j++){
#pragma unroll
      for(int rr=0;rr<4;rr++){
        int row = m0 + i*16 + q*4 + rr;
        int col = n0 + j*16 + r;
        float v = acc[i][j][rr];
        if(EBIAS) v += bias[col];
        if(ERELU) v = fmaxf(v, 0.f);
        if(OBF16) Cb[(size_t)row*N + col] = f2bf(v);
        else      Cf[(size_t)row*N + col] = v;
      }
    }
  }
}

// ---------------- Hop final GEMM: out[t] = h2bf[t] @ fcsum^T + fcb ; 128x128 tiles ------
__global__ __launch_bounds__(256) void hop_gemm(
    const short* __restrict__ Abf, const short* __restrict__ Bbf,
    const float* __restrict__ bias, float* __restrict__ out)
{
  const int lane = threadIdx.x & 63;
  const int wv   = threadIdx.x >> 6;
  const int wi = wv >> 1, wj = wv & 1;
  const int q = lane >> 4, r = lane & 15;
  const int t  = blockIdx.z;
  const int m0 = blockIdx.y * 128 + wi * 64;
  const int n0 = blockIdx.x * 128 + wj * 64;
  const short* Ab = Abf + (size_t)t * N_ * 128;

  f32x4 acc[4][4];
#pragma unroll
  for(int i=0;i<4;i++)
#pragma unroll
    for(int j=0;j<4;j++) acc[i][j] = (f32x4){0.f,0.f,0.f,0.f};

#pragma unroll
  for(int k0=0;k0<128;k0+=32){
    const int ka = k0 + q*8;
    short8 af[4], bfr[4];
#pragma unroll
    for(int i=0;i<4;i++) af[i]  = *(const short8*)(Ab  + (size_t)(m0 + i*16 + r)*128 + ka);
#pragma unroll
    for(int j=0;j<4;j++) bfr[j] = *(const short8*)(Bbf + (size_t)(n0 + j*16 + r)*128 + ka);
#pragma unroll
    for(int i=0;i<4;i++)
#pragma unroll
      for(int j=0;j<4;j++)
        acc[i][j] = __builtin_amdgcn_mfma_f32_16x16x32_bf16(af[i], bfr[j], acc[i][j], 0,0,0);
  }

#pragma unroll
  for(int i=0;i<4;i++){
#pragma unroll
    for(int j=0;j<4;j++){
#pragma unroll
      for(int rr=0;rr<4;rr++){
        int row = m0 + i*16 + q*4 + rr;
        int col = n0 + j*16 + r;
        out[((size_t)t*N_ + row)*N_ + col] = acc[i][j][rr] + bias[col];
      }
    }
  }
}

// ---------------- GAT layer 1 (H=4, C=128) ----------------------------------------------
// prep: snapshot rows<2048 of xw1 into x1s and compute attention dots (wave h per head)
__global__ __launch_bounds__(256) void k_prep1(const float* __restrict__ xw1,
    const float* __restrict__ atts, const float* __restrict__ attd,
    float* __restrict__ x1s, float* __restrict__ as1, float* __restrict__ ad1){
  int d = blockIdx.x;
  int tid = threadIdx.x;                 // 256: 2 channels each
  int h = tid >> 6, lane = tid & 63;
  float2 v = *(const float2*)(xw1 + (size_t)d*512 + tid*2);
  *(float2*)(x1s + (size_t)d*512 + tid*2) = v;
  int c = lane*2;                        // channel within head
  float2 a = *(const float2*)(atts + h*128 + c);
  float2 b = *(const float2*)(attd + h*128 + c);
  float s  = v.x*a.x + v.y*a.y;
  float dd = v.x*b.x + v.y*b.y;
  for(int o=32;o;o>>=1){ s += __shfl_down(s,o); dd += __shfl_down(dd,o); }
  if(lane == 0){ as1[d*4+h] = s; ad1[d*4+h] = dd; }
}

// denominators + CSR-ordered numerator stash. wave = timestep.
__global__ __launch_bounds__(1024) void k_den1(
    const int* __restrict__ off, const int* __restrict__ csr,
    const float* __restrict__ as1, const float* __restrict__ ad1,
    float* __restrict__ p1s, float* __restrict__ den1){
  int d = blockIdx.x;
  int t = threadIdx.x >> 6;
  int lane = threadIdx.x & 63;
  __shared__ float sden[16][4];
  float ad[4];
#pragma unroll
  for(int h=0;h<4;h++) ad[h] = ad1[d*4+h];
  float sum[4] = {0.f,0.f,0.f,0.f};
  int key = t*N_ + d;
  int beg = off[key], end = off[key+1];
  for(int k=beg+lane; k<end; k+=64){
    int s = csr[k] & (N_-1);
#pragma unroll
    for(int h=0;h<4;h++){
      float p = expf(lrelu(as1[s*4+h] + ad[h]));
      p1s[(size_t)k*4+h] = p;
      sum[h] += p;
    }
  }
#pragma unroll
  for(int h=0;h<4;h++)
    for(int o=32;o;o>>=1) sum[h] += __shfl_down(sum[h], o);
  if(lane == 0){
#pragma unroll
    for(int h=0;h<4;h++) sden[t][h] = sum[h];
  }
  __syncthreads();
  if(threadIdx.x < 4){
    int h = threadIdx.x;
    float s = 0.f;
#pragma unroll
    for(int w=0;w<16;w++) s += sden[w][h];
    den1[d*4+h] = s + expf(lrelu(as1[d*4+h] + ad[h]));
  }
}

// gather rows<2048, in place into xw1. 8 edge-groups x 128 channel-threads (float4 each).
__global__ __launch_bounds__(1024) void k_z1g(
    const int* __restrict__ off, const int* __restrict__ csr,
    const float* __restrict__ p1s, const float* __restrict__ den1,
    const float* __restrict__ as1, const float* __restrict__ ad1,
    const float* __restrict__ x1s, float* __restrict__ xw1){
  int d = blockIdx.x;
  int grp = threadIdx.x >> 7;            // 0..7
  int cid = threadIdx.x & 127;           // float4 id (4 channels)
  int h = cid >> 5;
  __shared__ f32x4 red[7][128];
  f32x4 acc = (f32x4){0.f,0.f,0.f,0.f};
  for(int t=grp; t<16; t+=8){
    int key = t*N_ + d;
    int beg = off[key], end = off[key+1];
    if(beg >= end) continue;
    int v = csr[beg];
    for(int k=beg; k<end; k++){
      int vn = (k+1<end) ? csr[k+1] : 0;
      int s = v & (N_-1);
      float p = p1s[(size_t)k*4 + h];
      f32x4 u = *(const f32x4*)(x1s + (size_t)s*512 + cid*4);
      acc += u * p;
      v = vn;
    }
  }
  if(grp) red[grp-1][cid] = acc;
  __syncthreads();
  if(grp == 0){
#pragma unroll
    for(int g=0; g<7; g++) acc += red[g][cid];
    float deninv = 1.f/(den1[d*4+h] + 1e-16f);
    float pself = expf(lrelu(as1[d*4+h] + ad1[d*4+h]));
    f32x4 v = *(const f32x4*)(x1s + (size_t)d*512 + cid*4);
    f32x4 o = (acc + v*pself) * deninv;
    *(f32x4*)(xw1 + (size_t)d*512 + cid*4) = o;
  }
}

// ---------------- GAT layer 2 (H=1, C=64) -----------------------------------------------
// xw2b already includes gat2_b (folded in GEMM). prep subtracts it for the att dots.
__global__ __launch_bounds__(256) void k_prep2(const float* __restrict__ xw2b,
    const float* __restrict__ atts, const float* __restrict__ attd,
    const float* __restrict__ b2,
    float* __restrict__ x2s, float* __restrict__ as2, float* __restrict__ ad2){
  int d = blockIdx.x*4 + (threadIdx.x >> 6);
  int lane = threadIdx.x & 63;
  float v = xw2b[(size_t)d*64 + lane];
  x2s[(size_t)d*64 + lane] = v;
  float vb = v - b2[lane];
  float s = vb*atts[lane], dd = vb*attd[lane];
  for(int o=32;o;o>>=1){ s += __shfl_down(s,o); dd += __shfl_down(dd,o); }
  if(lane == 0){ as2[d] = s; ad2[d] = dd; }
}

__global__ __launch_bounds__(1024) void k_den2(
    const int* __restrict__ off, const int* __restrict__ csr,
    const float* __restrict__ as2, const float* __restrict__ ad2,
    float* __restrict__ p2s, float* __restrict__ den2){
  int d = blockIdx.x;
  int t = threadIdx.x >> 6;
  int lane = threadIdx.x & 63;
  __shared__ float sden[16];
  float ad = ad2[d];
  float sum = 0.f;
  int key = t*N_ + d;
  int beg = off[key], end = off[key+1];
  for(int k=beg+lane; k<end; k+=64){
    int s = csr[k] & (N_-1);
    float p = expf(lrelu(as2[s] + ad));
    p2s[k] = p;
    sum += p;
  }
  for(int o=32;o;o>>=1) sum += __shfl_down(sum, o);
  if(lane == 0) sden[t] = sum;
  __syncthreads();
  if(threadIdx.x == 0){
    float s = 0.f;
#pragma unroll
    for(int w=0;w<16;w++) s += sden[w];
    den2[d] = s + expf(lrelu(as2[d] + ad));
  }
}

// gather rows<2048, in place into xw2b (bias folded: sum(alpha)~=1). wave = timestep.
__global__ __launch_bounds__(1024) void k_z2g(
    const int* __restrict__ off, const int* __restrict__ csr,
    const float* __restrict__ p2s, const float* __restrict__ den2,
    const float* __restrict__ as2, const float* __restrict__ ad2,
    const float* __restrict__ x2s, float* __restrict__ xw2b){
  int d = blockIdx.x;
  int t = threadIdx.x >> 6;
  int lane = threadIdx.x & 63;
  __shared__ float red[16][64];
  float acc = 0.f;
  int key = t*N_ + d;
  int beg = off[key], end = off[key+1];
  if(beg < end){
    int v = csr[beg];
    for(int k=beg; k<end; k++){
      int vn = (k+1<end) ? csr[k+1] : 0;
      int s = v & (N_-1);
      acc += p2s[k] * x2s[(size_t)s*64 + lane];
      v = vn;
    }
  }
  red[t][lane] = acc;
  __syncthreads();
  if(t == 0){
    float tot = 0.f;
#pragma unroll
    for(int w=0;w<16;w++) tot += red[w][lane];
    float deninv = 1.f/(den2[d] + 1e-16f);
    float pself = expf(lrelu(as2[d] + ad2[d]));
    xw2b[(size_t)d*64 + lane] = (tot + pself*x2s[(size_t)d*64 + lane]) * deninv;
  }
}

__global__ void k_linkpred(const float* __restrict__ z2, const int* __restrict__ eli,
                           float* __restrict__ out){
  int pair = blockIdx.x*4 + (threadIdx.x >> 6);
  int lane = threadIdx.x & 63;
  if(pair >= EL_) return;
  int a = eli[pair], b = eli[EL_ + pair];
  float v = z2[(size_t)a*64 + lane] * z2[(size_t)b*64 + lane];
  for(int off=32; off; off >>= 1) v += __shfl_down(v, off);
  if(lane == 0) out[pair] = v;
}

// ---------------- GCN gather: out[node] = self + sum coef*feats[src] --------------------
template<int F>
__global__ __launch_bounds__(F) void k_gcng(
    const float* __restrict__ coef, const float* __restrict__ dinv,
    const float* __restrict__ feats, const int* __restrict__ off,
    const int* __restrict__ csr, float* __restrict__ out){
  int node = blockIdx.x;
  int ch = threadIdx.x;
  int t = node >> 11;
  float di = dinv[node];
  float acc = di*di*feats[(size_t)node*F + ch];
  int beg = off[node], end = off[node+1];
  if(beg < end){
    int v = csr[beg];
    for(int k=beg; k<end; k++){
      int vn = (k+1<end) ? csr[k+1] : 0;
      int eid = v >> 11;
      int gs = (t << 11) | (v & (N_-1));
      acc += coef[eid]*feats[(size_t)gs*F + ch];
      v = vn;
    }
  }
  out[(size_t)node*F + ch] = acc;
}

// ---------------- launcher --------------------------------------------------------------
extern "C" void kernel_launch(void* const* d_in, const int* in_sizes, int n_in,
                              void* d_out, int out_size, void* d_ws, size_t ws_size,
                              hipStream_t stream) {
  const float* x       = (const float*)d_in[0];
  const int*   ei      = (const int*)d_in[1];
  const float* eattr   = (const float*)d_in[2];
  const int*   eli     = (const int*)d_in[3];
  const float* conv1_w = (const float*)d_in[4];
  const float* conv1_b = (const float*)d_in[5];
  const float* conv2_w = (const float*)d_in[6];
  const float* conv2_b = (const float*)d_in[7];
  const float* gat1_w  = (const float*)d_in[8];
  const float* g1as    = (const float*)d_in[9];
  const float* g1ad    = (const float*)d_in[10];
  const float* gat1_b  = (const float*)d_in[11];
  const float* gat2_w  = (const float*)d_in[12];
  const float* g2as    = (const float*)d_in[13];
  const float* g2ad    = (const float*)d_in[14];
  const float* gat2_b  = (const float*)d_in[15];
  const float* fcw     = (const float*)d_in[16];
  const float* fcb     = (const float*)d_in[17];

  // workspace carve
  char* wp = (char*)d_ws;
  auto alloc = [&](size_t bytes)->void*{ void* r = wp; wp += (bytes + 255) & ~(size_t)255; return r; };
  int*   cnt   = (int*)alloc((size_t)NT*4);
  int*   off   = (int*)alloc((size_t)(NT+1)*4);
  int*   cur   = (int*)alloc((size_t)NT*4);
  int*   csr   = (int*)alloc((size_t)EALL*4);
  float* as1   = (float*)alloc((size_t)N_*4*4);
  float* ad1   = (float*)alloc((size_t)N_*4*4);
  float* den1  = (float*)alloc((size_t)N_*4*4);
  float* p1s   = (float*)alloc((size_t)EALL*4*4);
  float* x1s   = (float*)alloc((size_t)N_*512*4);
  float* xw2b  = (float*)alloc((size_t)NT*64*4);
  float* as2   = (float*)alloc((size_t)N_*4);
  float* ad2   = (float*)alloc((size_t)N_*4);
  float* den2  = (float*)alloc((size_t)N_*4);
  float* p2s   = (float*)alloc((size_t)EALL*4);
  float* x2s   = (float*)alloc((size_t)N_*64*4);
  float* dinv  = (float*)alloc((size_t)NT*4);
  float* coef  = (float*)alloc((size_t)EALL*4);
  float* accx  = (float*)alloc((size_t)NT*64*4);
  float* h1    = (float*)alloc((size_t)NT*128*4);
  float* acch  = (float*)alloc((size_t)NT*128*4);
  short* h2bf  = (short*)alloc((size_t)NT*128*2);
  short* fcsbf = (short*)alloc((size_t)N_*128*2);

  // d_out layout: [0:8192) link_pred, [8192:...) hop_out (16*2048*2048).
  // Hop region doubles as scratch for the 64MB xw1 buffer (consumed before hop_gemm).
  float* outf     = (float*)d_out;
  float* link_out = outf;
  float* hop_out  = outf + EL_;
  float* xw1      = hop_out;                       // 16,777,216 floats

  dim3 blk(256);

  // ---- CSR build ----
  k_init<<<dim3(128+1024), blk, 0, stream>>>(fcw, fcsbf, cnt);
  k_cnt<<<dim3(EALL/256), blk, 0, stream>>>(ei, cnt);
  k_scan<<<dim3(1), dim3(1024), 0, stream>>>(cnt, off, cur);
  k_fill<<<dim3(EALL/256), blk, 0, stream>>>(ei, cur, csr);
  k_degg<<<dim3(NT/256), blk, 0, stream>>>(eattr, off, csr, dinv);
  k_coef<<<dim3(EALL/256), blk, 0, stream>>>(ei, eattr, dinv, coef);

  // ---- GAT branch ----
  gemm_bt<2,4,false,false,false,false><<<dim3(4,512), blk, 0, stream>>>(
      x, nullptr, gat1_w, nullptr, xw1, nullptr, 64, 512);
  k_prep1<<<dim3(N_), blk, 0, stream>>>(xw1, g1as, g1ad, x1s, as1, ad1);
  k_den1<<<dim3(N_), dim3(1024), 0, stream>>>(off, csr, as1, ad1, p1s, den1);
  k_z1g<<<dim3(N_), dim3(1024), 0, stream>>>(off, csr, p1s, den1, as1, ad1, x1s, xw1);
  gemm_bt<2,2,true,true,false,false><<<dim3(1,512), blk, 0, stream>>>(
      xw1, gat1_b, gat2_w, gat2_b, xw2b, nullptr, 512, 64);
  k_prep2<<<dim3(N_/4), blk, 0, stream>>>(xw2b, g2as, g2ad, gat2_b, x2s, as2, ad2);
  k_den2<<<dim3(N_), dim3(1024), 0, stream>>>(off, csr, as2, ad2, p2s, den2);
  k_z2g<<<dim3(N_), dim3(1024), 0, stream>>>(off, csr, p2s, den2, as2, ad2, x2s, xw2b);
  k_linkpred<<<dim3(EL_/4), blk, 0, stream>>>(xw2b, eli, link_out);

  // ---- hop (GCN) branch ----
  k_gcng<64><<<dim3(NT), dim3(64), 0, stream>>>(coef, dinv, x, off, csr, accx);
  gemm_bt<2,4,false,true,true,false><<<dim3(1,512), blk, 0, stream>>>(
      accx, nullptr, conv1_w, conv1_b, h1, nullptr, 64, 128);
  k_gcng<128><<<dim3(NT), dim3(128), 0, stream>>>(coef, dinv, h1, off, csr, acch);
  gemm_bt<2,4,false,true,true,true><<<dim3(1,512), blk, 0, stream>>>(
      acch, nullptr, conv2_w, conv2_b, nullptr, h2bf, 128, 128);
  hop_gemm<<<dim3(16,16,16), blk, 0, stream>>>(h2bf, fcsbf, fcb, hop_out);
}

// Round 3
// 636.019 us; speedup vs baseline: 1.0726x; 1.0726x over previous
//
#include <hip/hip_runtime.h>
#include <stdint.h>

typedef __attribute__((ext_vector_type(8))) short short8;
typedef __attribute__((ext_vector_type(4))) float f32x4;

#define T_   16
#define N_   2048
#define E_   16384
#define NT   32768      // T*N
#define EALL 262144     // T*E
#define EL_  8192

static __device__ __forceinline__ short f2bf(float f){
  union { float f; uint32_t u; } v; v.f = f;
  uint32_t r = (v.u + 0x7FFFu + ((v.u >> 16) & 1u)) >> 16;
  return (short)r;
}
static __device__ __forceinline__ float lrelu(float x){ return x > 0.f ? x : 0.2f*x; }

// ---------------- init: zero cnt + fcsum (independent work, fused) ----------------------
__global__ void k_init(const float* __restrict__ fcw, short* __restrict__ wbf,
                       int* __restrict__ cnt){
  int b = blockIdx.x;
  if(b < 128){
    cnt[b*256 + threadIdx.x] = 0;
  } else {
    int id = (b-128)*256 + threadIdx.x;      // N_*128 = 262144 -> 1024 blocks
    int j = id >> 7, k = id & 127;
    wbf[id] = f2bf(fcw[j*256 + k] + fcw[j*256 + 128 + k]);
  }
}

// ---------------- CSR build: key = t*2048 + dst; value packs (eid<<11)|src -------------
__global__ void k_cnt(const int* __restrict__ ei, int* __restrict__ cnt){
  int id = blockIdx.x*256 + threadIdx.x;
  if(id >= EALL) return;
  int t = id >> 14, e = id & (E_-1);
  int d = ei[t*2*E_ + E_ + e];
  atomicAdd(&cnt[t*N_ + d], 1);
}
__global__ __launch_bounds__(1024) void k_scan(const int* __restrict__ cnt,
                                               int* __restrict__ off, int* __restrict__ cur){
  __shared__ int part[1024];
  int tid = threadIdx.x;
  int base = tid*32;
  int loc[32]; int s = 0;
#pragma unroll
  for(int i=0;i<32;i++){ loc[i] = s; s += cnt[base+i]; }
  part[tid] = s; __syncthreads();
  for(int d=1; d<1024; d<<=1){
    int v = (tid>=d) ? part[tid-d] : 0;
    __syncthreads();
    part[tid] += v;
    __syncthreads();
  }
  int pre = (tid==0) ? 0 : part[tid-1];
#pragma unroll
  for(int i=0;i<32;i++){ int v = pre + loc[i]; off[base+i] = v; cur[base+i] = v; }
  if(tid == 1023) off[NT] = part[1023];
}
__global__ void k_fill(const int* __restrict__ ei, int* __restrict__ cur, int* __restrict__ csr){
  int id = blockIdx.x*256 + threadIdx.x;
  if(id >= EALL) return;
  int t = id >> 14, e = id & (E_-1);
  int s = ei[t*2*E_ + e];
  int d = ei[t*2*E_ + E_ + e];
  int pos = atomicAdd(&cur[t*N_ + d], 1);
  csr[pos] = (id << 11) | s;          // eid (18b) | src (11b)
}

// dinv[node] = 1/sqrt(1 + sum ew over incoming edges)
__global__ void k_degg(const float* __restrict__ ew, const int* __restrict__ off,
                       const int* __restrict__ csr, float* __restrict__ dinv){
  int n = blockIdx.x*256 + threadIdx.x;
  if(n >= NT) return;
  float s = 1.0f;
  for(int k=off[n]; k<off[n+1]; k++) s += ew[csr[k] >> 11];
  dinv[n] = rsqrtf(s);
}

// per-edge GCN coefficient (shared by both GCN layers)
__global__ void k_coef(const int* __restrict__ ei, const float* __restrict__ ew,
                       const float* __restrict__ dinv, float* __restrict__ coef){
  int id = blockIdx.x*256 + threadIdx.x;
  if(id >= EALL) return;
  int t = id >> 14, e = id & (E_-1);
  int s = ei[t*2*E_ + e];
  int d = ei[t*2*E_ + E_ + e];
  coef[id] = dinv[t*N_ + s] * ew[id] * dinv[t*N_ + d];
}

// ---------------- MFMA GEMM: C[M,N] = act(A[M,K]) @ B[N,K]^T (+bias)(+relu) -------------
template<int TM,int TN,bool PREACT,bool EBIAS,bool ERELU,bool OBF16>
__global__ __launch_bounds__(256) void gemm_bt(
    const float* __restrict__ A, const float* __restrict__ ab,
    const float* __restrict__ B, const float* __restrict__ bias,
    float* __restrict__ Cf, short* __restrict__ Cb, int K, int N)
{
  const int lane = threadIdx.x & 63;
  const int wv   = threadIdx.x >> 6;
  const int wi = wv >> 1, wj = wv & 1;
  const int q = lane >> 4, r = lane & 15;
  const int m0 = blockIdx.y * (2*TM*16) + wi * (TM*16);
  const int n0 = blockIdx.x * (2*TN*16) + wj * (TN*16);

  f32x4 acc[TM][TN];
#pragma unroll
  for(int i=0;i<TM;i++)
#pragma unroll
    for(int j=0;j<TN;j++) acc[i][j] = (f32x4){0.f,0.f,0.f,0.f};

  for(int k0=0;k0<K;k0+=32){
    const int ka = k0 + q*8;
    short8 af[TM], bfr[TN];
#pragma unroll
    for(int i=0;i<TM;i++){
      const float* p = A + (size_t)(m0 + i*16 + r)*K + ka;
      float4 u0 = *(const float4*)p;
      float4 u1 = *(const float4*)(p+4);
      float vv[8] = {u0.x,u0.y,u0.z,u0.w,u1.x,u1.y,u1.z,u1.w};
      if (PREACT){
        const float* bb = ab + ka;
        float4 b0 = *(const float4*)bb;
        float4 b1 = *(const float4*)(bb+4);
        float bv[8] = {b0.x,b0.y,b0.z,b0.w,b1.x,b1.y,b1.z,b1.w};
#pragma unroll
        for(int u=0;u<8;u++) vv[u] = fmaxf(vv[u]+bv[u], 0.f);
      }
      short8 s;
#pragma unroll
      for(int u=0;u<8;u++) s[u] = f2bf(vv[u]);
      af[i] = s;
    }
#pragma unroll
    for(int j=0;j<TN;j++){
      const float* p = B + (size_t)(n0 + j*16 + r)*K + ka;
      float4 u0 = *(const float4*)p;
      float4 u1 = *(const float4*)(p+4);
      float vv[8] = {u0.x,u0.y,u0.z,u0.w,u1.x,u1.y,u1.z,u1.w};
      short8 s;
#pragma unroll
      for(int u=0;u<8;u++) s[u] = f2bf(vv[u]);
      bfr[j] = s;
    }
#pragma unroll
    for(int i=0;i<TM;i++)
#pragma unroll
      for(int j=0;j<TN;j++)
        acc[i][j] = __builtin_amdgcn_mfma_f32_16x16x32_bf16(af[i], bfr[j], acc[i][j], 0,0,0);
  }

#pragma unroll
  for(int i=0;i<TM;i++){
#pragma unroll
    for(int j=0;j<TN;j++){
#pragma unroll
      for(int rr=0;rr<4;rr++){
        int row = m0 + i*16 + q*4 + rr;
        int col = n0 + j*16 + r;
        float v = acc[i][j][rr];
        if(EBIAS) v += bias[col];
        if(ERELU) v = fmaxf(v, 0.f);
        if(OBF16) Cb[(size_t)row*N + col] = f2bf(v);
        else      Cf[(size_t)row*N + col] = v;
      }
    }
  }
}

// ---------------- Hop final GEMM: out[t] = h2bf[t] @ fcsum^T + fcb ; 128x128 tiles ------
__global__ __launch_bounds__(256) void hop_gemm(
    const short* __restrict__ Abf, const short* __restrict__ Bbf,
    const float* __restrict__ bias, float* __restrict__ out)
{
  const int lane = threadIdx.x & 63;
  const int wv   = threadIdx.x >> 6;
  const int wi = wv >> 1, wj = wv & 1;
  const int q = lane >> 4, r = lane & 15;
  const int t  = blockIdx.z;
  const int m0 = blockIdx.y * 128 + wi * 64;
  const int n0 = blockIdx.x * 128 + wj * 64;
  const short* Ab = Abf + (size_t)t * N_ * 128;

  f32x4 acc[4][4];
#pragma unroll
  for(int i=0;i<4;i++)
#pragma unroll
    for(int j=0;j<4;j++) acc[i][j] = (f32x4){0.f,0.f,0.f,0.f};

#pragma unroll
  for(int k0=0;k0<128;k0+=32){
    const int ka = k0 + q*8;
    short8 af[4], bfr[4];
#pragma unroll
    for(int i=0;i<4;i++) af[i]  = *(const short8*)(Ab  + (size_t)(m0 + i*16 + r)*128 + ka);
#pragma unroll
    for(int j=0;j<4;j++) bfr[j] = *(const short8*)(Bbf + (size_t)(n0 + j*16 + r)*128 + ka);
#pragma unroll
    for(int i=0;i<4;i++)
#pragma unroll
      for(int j=0;j<4;j++)
        acc[i][j] = __builtin_amdgcn_mfma_f32_16x16x32_bf16(af[i], bfr[j], acc[i][j], 0,0,0);
  }

#pragma unroll
  for(int i=0;i<4;i++){
#pragma unroll
    for(int j=0;j<4;j++){
#pragma unroll
      for(int rr=0;rr<4;rr++){
        int row = m0 + i*16 + q*4 + rr;
        int col = n0 + j*16 + r;
        out[((size_t)t*N_ + row)*N_ + col] = acc[i][j][rr] + bias[col];
      }
    }
  }
}

// ---------------- GAT layer 1 (H=4, C=128) ----------------------------------------------
// prep: snapshot rows<2048 of xw1 into x1s and compute attention dots (wave h per head)
__global__ __launch_bounds__(256) void k_prep1(const float* __restrict__ xw1,
    const float* __restrict__ atts, const float* __restrict__ attd,
    float* __restrict__ x1s, float* __restrict__ as1, float* __restrict__ ad1){
  int d = blockIdx.x;
  int tid = threadIdx.x;                 // 256: 2 channels each
  int h = tid >> 6, lane = tid & 63;
  float2 v = *(const float2*)(xw1 + (size_t)d*512 + tid*2);
  *(float2*)(x1s + (size_t)d*512 + tid*2) = v;
  int c = lane*2;                        // channel within head
  float2 a = *(const float2*)(atts + h*128 + c);
  float2 b = *(const float2*)(attd + h*128 + c);
  float s  = v.x*a.x + v.y*a.y;
  float dd = v.x*b.x + v.y*b.y;
  for(int o=32;o;o>>=1){ s += __shfl_down(s,o); dd += __shfl_down(dd,o); }
  if(lane == 0){ as1[d*4+h] = s; ad1[d*4+h] = dd; }
}

// fused gather+softmax, rows<2048, in place into xw1.
// 8 edge-groups x 128 channel-threads (float4 each); denominator reduced in LDS.
__global__ __launch_bounds__(1024) void k_z1g(
    const int* __restrict__ off, const int* __restrict__ csr,
    const float* __restrict__ as1, const float* __restrict__ ad1,
    const float* __restrict__ x1s, float* __restrict__ xw1){
  int d = blockIdx.x;
  int grp = threadIdx.x >> 7;            // 0..7
  int cid = threadIdx.x & 127;           // float4 id (4 channels)
  int h = cid >> 5;
  __shared__ f32x4 red[7][128];
  __shared__ float redd[8][128];
  float adh = ad1[d*4+h];
  f32x4 acc = (f32x4){0.f,0.f,0.f,0.f};
  float dsum = 0.f;
  for(int t=grp; t<16; t+=8){
    int key = t*N_ + d;
    int beg = off[key], end = off[key+1];
    for(int k=beg; k<end; k++){
      int s = csr[k] & (N_-1);
      float p = expf(lrelu(as1[s*4+h] + adh));
      dsum += p;
      f32x4 u = *(const f32x4*)(x1s + (size_t)s*512 + cid*4);
      acc += u * p;
    }
  }
  if(grp) red[grp-1][cid] = acc;
  redd[grp][cid] = dsum;
  __syncthreads();
  if(grp == 0){
#pragma unroll
    for(int g=0; g<7; g++) acc += red[g][cid];
    float den = 0.f;
#pragma unroll
    for(int g=0; g<8; g++) den += redd[g][cid];
    float pself = expf(lrelu(as1[d*4+h] + adh));
    float deninv = 1.f/(den + pself + 1e-16f);
    f32x4 v = *(const f32x4*)(x1s + (size_t)d*512 + cid*4);
    f32x4 o = (acc + v*pself) * deninv;
    *(f32x4*)(xw1 + (size_t)d*512 + cid*4) = o;
  }
}

// ---------------- GAT layer 2 (H=1, C=64) -----------------------------------------------
// xw2b already includes gat2_b (folded in GEMM). prep subtracts it for the att dots.
__global__ __launch_bounds__(256) void k_prep2(const float* __restrict__ xw2b,
    const float* __restrict__ atts, const float* __restrict__ attd,
    const float* __restrict__ b2,
    float* __restrict__ x2s, float* __restrict__ as2, float* __restrict__ ad2){
  int d = blockIdx.x*4 + (threadIdx.x >> 6);
  int lane = threadIdx.x & 63;
  float v = xw2b[(size_t)d*64 + lane];
  x2s[(size_t)d*64 + lane] = v;
  float vb = v - b2[lane];
  float s = vb*atts[lane], dd = vb*attd[lane];
  for(int o=32;o;o>>=1){ s += __shfl_down(s,o); dd += __shfl_down(dd,o); }
  if(lane == 0){ as2[d] = s; ad2[d] = dd; }
}

// fused gather+softmax, rows<2048, in place into xw2b (bias folded: sum(alpha)~=1).
// wave = timestep; denominator reduced in LDS.
__global__ __launch_bounds__(1024) void k_z2g(
    const int* __restrict__ off, const int* __restrict__ csr,
    const float* __restrict__ as2, const float* __restrict__ ad2,
    const float* __restrict__ x2s, float* __restrict__ xw2b){
  int d = blockIdx.x;
  int t = threadIdx.x >> 6;
  int lane = threadIdx.x & 63;
  __shared__ float red[16][64];
  __shared__ float redd[16];
  float ad = ad2[d];
  float acc = 0.f, dsum = 0.f;
  int key = t*N_ + d;
  int beg = off[key], end = off[key+1];
  for(int k=beg; k<end; k++){
    int s = csr[k] & (N_-1);
    float p = expf(lrelu(as2[s] + ad));
    dsum += p;
    acc += p * x2s[(size_t)s*64 + lane];
  }
  red[t][lane] = acc;
  if(lane == 0) redd[t] = dsum;
  __syncthreads();
  if(t == 0){
    float tot = 0.f, den = 0.f;
#pragma unroll
    for(int w=0;w<16;w++){ tot += red[w][lane]; den += redd[w]; }
    float pself = expf(lrelu(as2[d] + ad));
    float deninv = 1.f/(den + pself + 1e-16f);
    xw2b[(size_t)d*64 + lane] = (tot + pself*x2s[(size_t)d*64 + lane]) * deninv;
  }
}

__global__ void k_linkpred(const float* __restrict__ z2, const int* __restrict__ eli,
                           float* __restrict__ out){
  int pair = blockIdx.x*4 + (threadIdx.x >> 6);
  int lane = threadIdx.x & 63;
  if(pair >= EL_) return;
  int a = eli[pair], b = eli[EL_ + pair];
  float v = z2[(size_t)a*64 + lane] * z2[(size_t)b*64 + lane];
  for(int off=32; off; off >>= 1) v += __shfl_down(v, off);
  if(lane == 0) out[pair] = v;
}

// ---------------- GCN gather: out[node] = self + sum coef*feats[src] --------------------
template<int F>
__global__ __launch_bounds__(F) void k_gcng(
    const float* __restrict__ coef, const float* __restrict__ dinv,
    const float* __restrict__ feats, const int* __restrict__ off,
    const int* __restrict__ csr, float* __restrict__ out){
  int node = blockIdx.x;
  int ch = threadIdx.x;
  int t = node >> 11;
  float di = dinv[node];
  float acc = di*di*feats[(size_t)node*F + ch];
  int beg = off[node], end = off[node+1];
  for(int k=beg; k<end; k++){
    int v = csr[k];
    int eid = v >> 11;
    int gs = (t << 11) | (v & (N_-1));
    acc += coef[eid]*feats[(size_t)gs*F + ch];
  }
  out[(size_t)node*F + ch] = acc;
}

// ---------------- launcher --------------------------------------------------------------
extern "C" void kernel_launch(void* const* d_in, const int* in_sizes, int n_in,
                              void* d_out, int out_size, void* d_ws, size_t ws_size,
                              hipStream_t stream) {
  const float* x       = (const float*)d_in[0];
  const int*   ei      = (const int*)d_in[1];
  const float* eattr   = (const float*)d_in[2];
  const int*   eli     = (const int*)d_in[3];
  const float* conv1_w = (const float*)d_in[4];
  const float* conv1_b = (const float*)d_in[5];
  const float* conv2_w = (const float*)d_in[6];
  const float* conv2_b = (const float*)d_in[7];
  const float* gat1_w  = (const float*)d_in[8];
  const float* g1as    = (const float*)d_in[9];
  const float* g1ad    = (const float*)d_in[10];
  const float* gat1_b  = (const float*)d_in[11];
  const float* gat2_w  = (const float*)d_in[12];
  const float* g2as    = (const float*)d_in[13];
  const float* g2ad    = (const float*)d_in[14];
  const float* gat2_b  = (const float*)d_in[15];
  const float* fcw     = (const float*)d_in[16];
  const float* fcb     = (const float*)d_in[17];

  // workspace carve
  char* wp = (char*)d_ws;
  auto alloc = [&](size_t bytes)->void*{ void* r = wp; wp += (bytes + 255) & ~(size_t)255; return r; };
  int*   cnt   = (int*)alloc((size_t)NT*4);
  int*   off   = (int*)alloc((size_t)(NT+1)*4);
  int*   cur   = (int*)alloc((size_t)NT*4);
  int*   csr   = (int*)alloc((size_t)EALL*4);
  float* as1   = (float*)alloc((size_t)N_*4*4);
  float* ad1   = (float*)alloc((size_t)N_*4*4);
  float* x1s   = (float*)alloc((size_t)N_*512*4);
  float* xw2b  = (float*)alloc((size_t)NT*64*4);
  float* as2   = (float*)alloc((size_t)N_*4);
  float* ad2   = (float*)alloc((size_t)N_*4);
  float* x2s   = (float*)alloc((size_t)N_*64*4);
  float* dinv  = (float*)alloc((size_t)NT*4);
  float* coef  = (float*)alloc((size_t)EALL*4);
  float* accx  = (float*)alloc((size_t)NT*64*4);
  float* h1    = (float*)alloc((size_t)NT*128*4);
  float* acch  = (float*)alloc((size_t)NT*128*4);
  short* h2bf  = (short*)alloc((size_t)NT*128*2);
  short* fcsbf = (short*)alloc((size_t)N_*128*2);

  // d_out layout: [0:8192) link_pred, [8192:...) hop_out (16*2048*2048).
  // Hop region doubles as scratch for the 64MB xw1 buffer (consumed before hop_gemm).
  float* outf     = (float*)d_out;
  float* link_out = outf;
  float* hop_out  = outf + EL_;
  float* xw1      = hop_out;                       // 16,777,216 floats

  dim3 blk(256);

  // ---- CSR build ----
  k_init<<<dim3(128+1024), blk, 0, stream>>>(fcw, fcsbf, cnt);
  k_cnt<<<dim3(EALL/256), blk, 0, stream>>>(ei, cnt);
  k_scan<<<dim3(1), dim3(1024), 0, stream>>>(cnt, off, cur);
  k_fill<<<dim3(EALL/256), blk, 0, stream>>>(ei, cur, csr);
  k_degg<<<dim3(NT/256), blk, 0, stream>>>(eattr, off, csr, dinv);
  k_coef<<<dim3(EALL/256), blk, 0, stream>>>(ei, eattr, dinv, coef);

  // ---- GAT branch ----
  gemm_bt<4,4,false,false,false,false><<<dim3(4,256), blk, 0, stream>>>(
      x, nullptr, gat1_w, nullptr, xw1, nullptr, 64, 512);
  k_prep1<<<dim3(N_), blk, 0, stream>>>(xw1, g1as, g1ad, x1s, as1, ad1);
  k_z1g<<<dim3(N_), dim3(1024), 0, stream>>>(off, csr, as1, ad1, x1s, xw1);
  gemm_bt<4,2,true,true,false,false><<<dim3(1,256), blk, 0, stream>>>(
      xw1, gat1_b, gat2_w, gat2_b, xw2b, nullptr, 512, 64);
  k_prep2<<<dim3(N_/4), blk, 0, stream>>>(xw2b, g2as, g2ad, gat2_b, x2s, as2, ad2);
  k_z2g<<<dim3(N_), dim3(1024), 0, stream>>>(off, csr, as2, ad2, x2s, xw2b);
  k_linkpred<<<dim3(EL_/4), blk, 0, stream>>>(xw2b, eli, link_out);

  // ---- hop (GCN) branch ----
  k_gcng<64><<<dim3(NT), dim3(64), 0, stream>>>(coef, dinv, x, off, csr, accx);
  gemm_bt<4,4,false,true,true,false><<<dim3(1,256), blk, 0, stream>>>(
      accx, nullptr, conv1_w, conv1_b, h1, nullptr, 64, 128);
  k_gcng<128><<<dim3(NT), dim3(128), 0, stream>>>(coef, dinv, h1, off, csr, acch);
  gemm_bt<4,4,false,true,true,true><<<dim3(1,256), blk, 0, stream>>>(
      acch, nullptr, conv2_w, conv2_b, nullptr, h2bf, 128, 128);
  hop_gemm<<<dim3(16,16,16), blk, 0, stream>>>(h2bf, fcsbf, fcb, hop_out);
}